// Round 3
// baseline (297.730 us; speedup 1.0000x reference)
//
#include <hip/hip_runtime.h>

// Problem constants (fixed by reference)
#define B_ 16
#define C_ 64
#define T_ 2048
#define O_ 64
#define KNN 3
#define JSPLIT 8
#define JCHUNK (T_ / JSPLIT)   // 256

// Workspace layout (float offsets). Total = 3,715,072 floats = 14.86 MB.
#define XT_OFF 0                                  // xT[b][t][c]  : B*T*C
#define WT_OFF (B_ * T_ * C_)                     // Wt[m][o] m=k*64+c : 192*64
#define NSQ_OFF (WT_OFF + 192 * O_)               // nsq[b*T+t]   : B*T
#define PD_OFF (NSQ_OFF + B_ * T_)                // partial dists: B*T*JSPLIT*3
#define PI_OFF (PD_OFF + B_ * T_ * JSPLIT * 3)    // partial idx  : B*T*JSPLIT*3

// ---------------------------------------------------------------------------
// Prep: transpose x (B,C,T) -> xT (B,T,C), nsq[b,t] = sum_c x^2,
//       W (O,C,K) -> Wt[k*64+c][o]
// ---------------------------------------------------------------------------
__global__ __launch_bounds__(256) void prep_kernel(const float* __restrict__ x,
                                                   const float* __restrict__ W,
                                                   float* __restrict__ ws) {
    float* xT  = ws + XT_OFF;
    float* Wt  = ws + WT_OFF;
    float* nsq = ws + NSQ_OFF;
    int blk = blockIdx.x;
    int tid = threadIdx.x;
    if (blk < B_ * (T_ / 64)) {
        int b  = blk / (T_ / 64);
        int t0 = (blk % (T_ / 64)) * 64;
        __shared__ float tl[64 * 65];
        #pragma unroll
        for (int r = 0; r < 16; ++r) {
            int e = r * 256 + tid;
            int c = e >> 6, t = e & 63;
            tl[c * 65 + t] = x[(b * C_ + c) * T_ + t0 + t];  // coalesced in t
        }
        __syncthreads();
        #pragma unroll
        for (int r = 0; r < 16; ++r) {
            int e = r * 256 + tid;
            int t = e >> 6, c = e & 63;
            xT[(b * T_ + t0 + t) * 64 + c] = tl[c * 65 + t];  // coalesced in c
        }
        if (tid < 64) {
            float s = 0.f;
            #pragma unroll
            for (int c = 0; c < 64; ++c) { float v = tl[c * 65 + tid]; s = fmaf(v, v, s); }
            nsq[b * T_ + t0 + tid] = s;
        }
    } else {
        // W transpose: e enumerates (o*64+c)*3+k (read-coalesced)
        int e = (blk - B_ * (T_ / 64)) * 256 + tid;
        if (e < O_ * C_ * KNN) {
            int o = e / (C_ * KNN);
            int c = (e / KNN) % C_;
            int k = e % KNN;
            Wt[(k * 64 + c) * O_ + o] = W[e];
        }
    }
}

// ---------------------------------------------------------------------------
// KNN: score s_j = nsq_j - 2*dot(x_i, x_j) (rank-equivalent to clamped dist).
// Lane owns ONE i-row (A = 64 VGPR). B rows + nsq_j are WAVE-UNIFORM loads ->
// scalar pipe (s_load), FMAs take the SGPR operand. No LDS, no barriers.
// 4096 single-wave blocks -> 4 waves/SIMD.
// ---------------------------------------------------------------------------
__global__ __launch_bounds__(64) void knn_topk_kernel(const float* __restrict__ xT,
                                                      const float* __restrict__ nsq,
                                                      float* __restrict__ pd,
                                                      int* __restrict__ pi) {
    int blk   = blockIdx.x;            // 0..4095
    int ib    = blk / JSPLIT;          // 64-row i-block, 0..511
    int q     = blk % JSPLIT;          // j chunk
    int b     = ib / (T_ / 64);
    int iBase = (ib % (T_ / 64)) * 64;
    int l     = threadIdx.x;           // lane
    const float* xTb  = xT + (size_t)b * T_ * 64;
    const float* nsqb = nsq + b * T_;

    float4 a[16];
    {
        const float4* rA = (const float4*)(xTb + (size_t)(iBase + l) * 64);
        #pragma unroll
        for (int c4 = 0; c4 < 16; ++c4) a[c4] = rA[c4];
    }

    const float INF = __builtin_inff();
    float d0 = INF, d1 = INF, d2 = INF;
    int   j0 = 0, j1 = 0, j2 = 0;

    int jstart = q * JCHUNK;
    #pragma unroll 2
    for (int j = jstart; j < jstart + JCHUNK; ++j) {
        const float4* br = (const float4*)(xTb + (size_t)j * 64);  // uniform addr
        float snj = nsqb[j];                                       // uniform addr
        float px = 0.f, py = 0.f, pz = 0.f, pw = 0.f;
        #pragma unroll
        for (int c4 = 0; c4 < 16; ++c4) {
            float4 w = br[c4];          // -> s_load; fmac with SGPR src0
            px = fmaf(w.x, a[c4].x, px); py = fmaf(w.y, a[c4].y, py);
            pz = fmaf(w.z, a[c4].z, pz); pw = fmaf(w.w, a[c4].w, pw);
        }
        float s = snj - 2.f * ((px + py) + (pz + pw));
        // branchless sorted top-3 insert; strict < => reference tie-break
        bool c2 = s < d2, c1 = s < d1, c0 = s < d0;
        float nd2 = c1 ? d1 : (c2 ? s : d2); int ni2 = c1 ? j1 : (c2 ? j : j2);
        float nd1 = c0 ? d0 : (c1 ? s : d1); int ni1 = c0 ? j0 : (c1 ? j : j1);
        float nd0 = c0 ? s : d0;             int ni0 = c0 ? j : j0;
        d2 = nd2; j2 = ni2; d1 = nd1; j1 = ni1; d0 = nd0; j0 = ni0;
    }

    int r    = b * T_ + iBase + l;
    int base = (r * JSPLIT + q) * 3;
    pd[base] = d0; pd[base + 1] = d1; pd[base + 2] = d2;
    pi[base] = j0; pi[base + 1] = j1; pi[base + 2] = j2;
}

// ---------------------------------------------------------------------------
// Merge: 1 thread per (b,i). Merges its own 24 partials (ascending-j chunk
// order, strict < => reference tie-break) and writes jsel in-place into the
// first 3 slots of its OWN pi region (thread-private -> no race).
// ---------------------------------------------------------------------------
__global__ __launch_bounds__(256) void merge_kernel(float* __restrict__ ws) {
    const float* pd = ws + PD_OFF;
    int*         pi = (int*)(ws + PI_OFF);
    int t = blockIdx.x * 256 + threadIdx.x;   // 0 .. B*T-1
    int base = t * (JSPLIT * 3);
    const float INF = __builtin_inff();
    float D0 = INF, D1 = INF, D2 = INF; int I0 = 0, I1 = 0, I2 = 0;
    #pragma unroll
    for (int qq = 0; qq < JSPLIT * 3; ++qq) {
        float d = pd[base + qq]; int id = pi[base + qq];
        if (d < D2) {
            if (d < D1) {
                D2 = D1; I2 = I1;
                if (d < D0) { D1 = D0; I1 = I0; D0 = d; I0 = id; }
                else        { D1 = d; I1 = id; }
            } else { D2 = d; I2 = id; }
        }
    }
    pi[base] = I0; pi[base + 1] = I1; pi[base + 2] = I2;
}

// ---------------------------------------------------------------------------
// Conv: block = (b, 64-wide i-tile), 256 threads. Stage Wt (48KB) + gathered
// neighbor tile g[m][i'] (48KB) in LDS; 16x16 thread grid computes 4o x 4i
// register tiles; float4 stores contiguous in i (coalesced, no write amp).
// ---------------------------------------------------------------------------
__global__ __launch_bounds__(256) void conv2_kernel(const float* __restrict__ ws,
                                                    const float* __restrict__ bias,
                                                    float* __restrict__ out) {
    const float* xT = ws + XT_OFF;
    const int*   pi = (const int*)(ws + PI_OFF);

    __shared__ float Wt_s[192 * 64];
    __shared__ float g_s[192 * 64];

    int b  = blockIdx.x >> 5;            // 32 i-tiles of 64
    int i0 = (blockIdx.x & 31) * 64;
    int tid = threadIdx.x;

    // stage Wt (coalesced float4 copy)
    {
        const float4* WtG = (const float4*)(ws + WT_OFF);
        float4* WtS = (float4*)Wt_s;
        #pragma unroll
        for (int r = 0; r < 12; ++r) WtS[r * 256 + tid] = WtG[r * 256 + tid];
    }
    // gather: 192 units (k, i'), each loads one neighbor row (256B contiguous)
    if (tid < 192) {
        int k  = tid >> 6;               // 0..2
        int ip = tid & 63;               // i' within tile
        int j  = pi[(b * T_ + i0 + ip) * (JSPLIT * 3) + k];
        const float4* src = (const float4*)(xT + ((size_t)b * T_ + j) * 64);
        #pragma unroll
        for (int c4 = 0; c4 < 16; ++c4) {
            float4 v = src[c4];
            int m = k * 64 + c4 * 4;
            g_s[(m + 0) * 64 + ip] = v.x;
            g_s[(m + 1) * 64 + ip] = v.y;
            g_s[(m + 2) * 64 + ip] = v.z;
            g_s[(m + 3) * 64 + ip] = v.w;
        }
    }
    __syncthreads();

    int oq = tid >> 4;                   // 0..15 -> o = oq*4..oq*4+3
    int iq = tid & 15;                   // 0..15 -> i' = iq*4..iq*4+3
    float acc[4][4] = {{0.f}};
    #pragma unroll 4
    for (int m = 0; m < 192; ++m) {
        float4 wv = *(const float4*)(Wt_s + m * 64 + oq * 4);  // broadcast x16
        float4 gv = *(const float4*)(g_s  + m * 64 + iq * 4);  // broadcast x4
        acc[0][0] = fmaf(wv.x, gv.x, acc[0][0]); acc[0][1] = fmaf(wv.x, gv.y, acc[0][1]);
        acc[0][2] = fmaf(wv.x, gv.z, acc[0][2]); acc[0][3] = fmaf(wv.x, gv.w, acc[0][3]);
        acc[1][0] = fmaf(wv.y, gv.x, acc[1][0]); acc[1][1] = fmaf(wv.y, gv.y, acc[1][1]);
        acc[1][2] = fmaf(wv.y, gv.z, acc[1][2]); acc[1][3] = fmaf(wv.y, gv.w, acc[1][3]);
        acc[2][0] = fmaf(wv.z, gv.x, acc[2][0]); acc[2][1] = fmaf(wv.z, gv.y, acc[2][1]);
        acc[2][2] = fmaf(wv.z, gv.z, acc[2][2]); acc[2][3] = fmaf(wv.z, gv.w, acc[2][3]);
        acc[3][0] = fmaf(wv.w, gv.x, acc[3][0]); acc[3][1] = fmaf(wv.w, gv.y, acc[3][1]);
        acc[3][2] = fmaf(wv.w, gv.z, acc[3][2]); acc[3][3] = fmaf(wv.w, gv.w, acc[3][3]);
    }
    #pragma unroll
    for (int po = 0; po < 4; ++po) {
        int o = oq * 4 + po;
        float bv = bias[o];
        float4 r;
        r.x = acc[po][0] + bv; r.y = acc[po][1] + bv;
        r.z = acc[po][2] + bv; r.w = acc[po][3] + bv;
        // contiguous in i across iq -> coalesced 256B segments per o-row
        *(float4*)(out + (b * O_ + o) * T_ + i0 + iq * 4) = r;
    }
}

// ---------------------------------------------------------------------------
extern "C" void kernel_launch(void* const* d_in, const int* in_sizes, int n_in,
                              void* d_out, int out_size, void* d_ws, size_t ws_size,
                              hipStream_t stream) {
    const float* x    = (const float*)d_in[0];
    const float* W    = (const float*)d_in[1];
    const float* bias = (const float*)d_in[2];
    float* out = (float*)d_out;
    float* ws  = (float*)d_ws;

    prep_kernel<<<B_ * (T_ / 64) + 48, 256, 0, stream>>>(x, W, ws);
    knn_topk_kernel<<<(B_ * T_ / 64) * JSPLIT, 64, 0, stream>>>(
        ws + XT_OFF, ws + NSQ_OFF, ws + PD_OFF, (int*)(ws + PI_OFF));
    merge_kernel<<<B_ * T_ / 256, 256, 0, stream>>>(ws);
    conv2_kernel<<<B_ * 32, 256, 0, stream>>>(ws, bias, out);
}

// Round 4
// 201.898 us; speedup vs baseline: 1.4747x; 1.4747x over previous
//
#include <hip/hip_runtime.h>

// Problem constants (fixed by reference)
#define B_ 16
#define C_ 64
#define T_ 2048
#define O_ 64
#define KNN 3

typedef short short8 __attribute__((ext_vector_type(8)));   // 8 bf16 (4 VGPRs)
typedef float f32x4  __attribute__((ext_vector_type(4)));

// Workspace layout (float offsets). Total = 5,287,936 floats = 21.2 MB.
#define XT_OFF 0                              // fp32 xT[b][t][c]        : B*T*64
#define XS_OFF (XT_OFF + B_ * T_ * C_)        // ushort xs[b][t][128] hi|lo : B*T*128 ushort = B*T*64 float slots
#define NSQ_OFF (XS_OFF + B_ * T_ * C_)       // fp32 nsq[b*T+t]         : B*T
#define WT_OFF (NSQ_OFF + B_ * T_)            // fp32 Wt[m][o], m=k*64+c : 192*64
#define CAND_OFF (WT_OFF + 192 * O_)          // int cand[B*T][32]       : B*T*32

__device__ inline ushort bf16_rne(float f) {
    union { float f; unsigned u; } cv; cv.f = f;
    unsigned u = cv.u;
    u += 0x7FFF + ((u >> 16) & 1);            // round-to-nearest-even
    return (ushort)(u >> 16);
}
__device__ inline float bf16_val(ushort h) {
    union { unsigned u; float f; } cv; cv.u = ((unsigned)h) << 16; return cv.f;
}

// ---------------------------------------------------------------------------
// Prep: x (B,C,T) -> xT (B,T,C) fp32, xs (B,T,128) bf16 [hi|lo], nsq,
//       W (O,C,K) -> Wt[k*64+c][o]
// ---------------------------------------------------------------------------
__global__ __launch_bounds__(256) void prep_kernel(const float* __restrict__ x,
                                                   const float* __restrict__ W,
                                                   float* __restrict__ ws) {
    float*  xT  = ws + XT_OFF;
    ushort* xs  = (ushort*)(ws + XS_OFF);
    float*  nsq = ws + NSQ_OFF;
    float*  Wt  = ws + WT_OFF;
    int blk = blockIdx.x;
    int tid = threadIdx.x;
    if (blk < B_ * (T_ / 64)) {
        int b  = blk / (T_ / 64);
        int t0 = (blk % (T_ / 64)) * 64;
        __shared__ float tl[64 * 65];
        #pragma unroll
        for (int r = 0; r < 16; ++r) {
            int e = r * 256 + tid;
            int c = e >> 6, t = e & 63;
            tl[c * 65 + t] = x[(b * C_ + c) * T_ + t0 + t];  // coalesced in t
        }
        __syncthreads();
        #pragma unroll
        for (int r = 0; r < 16; ++r) {
            int e = r * 256 + tid;
            int t = e >> 6, c = e & 63;
            float v = tl[c * 65 + t];
            size_t rowg = (size_t)(b * T_ + t0 + t);
            xT[rowg * 64 + c] = v;
            ushort hi = bf16_rne(v);
            float  fr = v - bf16_val(hi);
            ushort lo = bf16_rne(fr);
            xs[rowg * 128 + c]      = hi;
            xs[rowg * 128 + 64 + c] = lo;
        }
        if (tid < 64) {
            float s = 0.f;
            #pragma unroll
            for (int c = 0; c < 64; ++c) { float v = tl[c * 65 + tid]; s = fmaf(v, v, s); }
            nsq[b * T_ + t0 + tid] = s;
        }
    } else {
        int e = (blk - B_ * (T_ / 64)) * 256 + tid;
        if (e < O_ * C_ * KNN) {
            int o = e / (C_ * KNN);
            int c = (e / KNN) % C_;
            int k = e % KNN;
            Wt[(k * 64 + c) * O_ + o] = W[e];
        }
    }
}

// ---------------------------------------------------------------------------
// KNN approx pass (MFMA): S^T(j,i) = nsq_j - 2*(hi_j.hi_i + lo_j.hi_i + hi_j.lo_i)
// via mfma_f32_16x16x32_bf16 over virtual K=192 (A=[hi|lo|hi], B=[hi|hi|lo]).
// C layout: col=lane&15 (=i), row=(lane>>4)*4+reg (=j) -> per-lane top-4 over
// its j-stripe; 2 halves x 4 stripes -> 32 candidates/row (set only; exact
// ranking happens in convref). Block: (b,h) group x 64-i tile, 4 waves.
// Grid swizzle: g=bid&31 -> XCD g%8 keeps each (b,h)'s j-data L2-local.
// ---------------------------------------------------------------------------
__global__ __launch_bounds__(256, 4) void knn_mfma_kernel(const ushort* __restrict__ xs,
                                                          const float* __restrict__ nsq,
                                                          int* __restrict__ cand) {
    __shared__ ushort jbuf[2][64 * 136];   // padded rows: 136 ushort = 272 B
    __shared__ float  nsqs[1024];

    int bid = blockIdx.x;
    int m   = bid >> 5;                    // i-tile 0..31
    int g   = bid & 31;                    // group = b*2 + h
    int b   = g >> 1, h = g & 1;
    int i0  = m * 64;
    int tid = threadIdx.x;
    int wq  = tid >> 6, l = tid & 63;
    int lr  = l & 15, lq = l >> 4;
    const ushort* xsb = xs + (size_t)b * T_ * 128;
    int jBase0 = h * 1024;

    // nsq half-chunk into LDS
    ((float4*)nsqs)[tid] = ((const float4*)(nsq + b * T_ + jBase0))[tid];

    // i-side (B-operand) frags in registers: virtual [hi|hi|lo]
    short8 bfrag[6];
    {
        const int Bmap[6] = {0, 32, 0, 32, 64, 96};
        const ushort* ib = xsb + (size_t)(i0 + wq * 16 + lr) * 128 + lq * 8;
        #pragma unroll
        for (int t = 0; t < 6; ++t) bfrag[t] = *(const short8*)(ib + Bmap[t]);
    }

    const float INF = __builtin_inff();
    float v0 = INF, v1 = INF, v2 = INF, v3 = INF;
    int   x0 = 0, x1 = 0, x2 = 0, x3 = 0;

    int   srow = tid >> 2, sseg = tid & 3;      // staging role: 64B per thread
    float4 st[4];

    // prologue: load + store subtile 0
    {
        const float4* gp = (const float4*)(xsb + (size_t)(jBase0 + srow) * 128 + sseg * 32);
        #pragma unroll
        for (int k = 0; k < 4; ++k) st[k] = gp[k];
        float4* dp = (float4*)(jbuf[0] + srow * 136 + sseg * 32);
        #pragma unroll
        for (int k = 0; k < 4; ++k) dp[k] = st[k];
    }

    #pragma unroll 1
    for (int js = 0; js < 16; ++js) {
        __syncthreads();                        // jbuf[js&1] + nsqs visible
        if (js < 15) {                          // prefetch next subtile
            const float4* gp = (const float4*)(xsb + (size_t)(jBase0 + (js + 1) * 64 + srow) * 128 + sseg * 32);
            #pragma unroll
            for (int k = 0; k < 4; ++k) st[k] = gp[k];
        }
        const ushort* jb = jbuf[js & 1];
        #pragma unroll
        for (int tile = 0; tile < 4; ++tile) {
            f32x4 acc = {0.f, 0.f, 0.f, 0.f};
            const ushort* ar = jb + (tile * 16 + lr) * 136 + lq * 8;
            // virtual A K-steps [hi|lo|hi] -> phys {0,32,64,96,0,32}
            acc = __builtin_amdgcn_mfma_f32_16x16x32_bf16(*(const short8*)(ar +  0), bfrag[0], acc, 0, 0, 0);
            acc = __builtin_amdgcn_mfma_f32_16x16x32_bf16(*(const short8*)(ar + 32), bfrag[1], acc, 0, 0, 0);
            acc = __builtin_amdgcn_mfma_f32_16x16x32_bf16(*(const short8*)(ar + 64), bfrag[2], acc, 0, 0, 0);
            acc = __builtin_amdgcn_mfma_f32_16x16x32_bf16(*(const short8*)(ar + 96), bfrag[3], acc, 0, 0, 0);
            acc = __builtin_amdgcn_mfma_f32_16x16x32_bf16(*(const short8*)(ar +  0), bfrag[4], acc, 0, 0, 0);
            acc = __builtin_amdgcn_mfma_f32_16x16x32_bf16(*(const short8*)(ar + 32), bfrag[5], acc, 0, 0, 0);
            int jql = js * 64 + tile * 16 + lq * 4;
            float4 nv = *(const float4*)(nsqs + jql);       // broadcast per 16-lane group
            float s0 = fmaf(-2.f, acc[0], nv.x);
            float s1 = fmaf(-2.f, acc[1], nv.y);
            float s2 = fmaf(-2.f, acc[2], nv.z);
            float s3 = fmaf(-2.f, acc[3], nv.w);
            int jg = jBase0 + jql;
            // branchless insert into sorted top-4 (candidate SET only)
            #define INS4(s, jj) { bool c3 = (s) < v3, c2 = (s) < v2, c1 = (s) < v1, c0 = (s) < v0; \
                float nv3 = c2 ? v2 : (c3 ? (s) : v3); int nx3 = c2 ? x2 : (c3 ? (jj) : x3); \
                float nv2 = c1 ? v1 : (c2 ? (s) : v2); int nx2 = c1 ? x1 : (c2 ? (jj) : x2); \
                float nv1 = c0 ? v0 : (c1 ? (s) : v1); int nx1 = c0 ? x0 : (c1 ? (jj) : x1); \
                v3 = nv3; x3 = nx3; v2 = nv2; x2 = nx2; v1 = nv1; x1 = nx1; \
                v0 = c0 ? (s) : v0; x0 = c0 ? (jj) : x0; }
            INS4(s0, jg + 0); INS4(s1, jg + 1); INS4(s2, jg + 2); INS4(s3, jg + 3);
            #undef INS4
        }
        if (js < 15) {                          // fill other buffer
            float4* dp = (float4*)(jbuf[(js + 1) & 1] + srow * 136 + sseg * 32);
            #pragma unroll
            for (int k = 0; k < 4; ++k) dp[k] = st[k];
        }
    }

    int row = b * T_ + i0 + wq * 16 + lr;
    int4 c4; c4.x = x0; c4.y = x1; c4.z = x2; c4.w = x3;
    *(int4*)(cand + (size_t)row * 32 + h * 16 + lq * 4) = c4;
}

// ---------------------------------------------------------------------------
// Fused refine + gather + conv. Block = (b, 64-i tile), 256 threads.
// Phase 1: exact fp32 re-rank of 32 candidates/row (R2's exact accumulation
//          order + (s,j) lexicographic tie-break == np top_k semantics).
// Phase 2: gather neighbor rows into LDS.  Phase 3: 4o x 4i register-tile conv.
// ---------------------------------------------------------------------------
__global__ __launch_bounds__(256) void convref_kernel(const float* __restrict__ ws,
                                                      const float* __restrict__ bias,
                                                      float* __restrict__ out) {
    const float* xT   = ws + XT_OFF;
    const float* nsq  = ws + NSQ_OFF;
    const int*   cand = (const int*)(ws + CAND_OFF);

    __shared__ float Wt_s[192 * 64];
    __shared__ float g_s[192 * 64];
    __shared__ float cs[64 * 12];
    __shared__ int   cj[64 * 12];
    __shared__ int   jsel[64 * 3];

    int b  = blockIdx.x >> 5;
    int i0 = (blockIdx.x & 31) * 64;
    int tid = threadIdx.x;

    // stage Wt
    {
        const float4* WtG = (const float4*)(ws + WT_OFF);
        float4* WtS = (float4*)Wt_s;
        #pragma unroll
        for (int r = 0; r < 12; ++r) WtS[r * 256 + tid] = WtG[r * 256 + tid];
    }

    // --- Phase 1: exact refine. 64 rows x 4 groups; each thread 8 candidates.
    {
        int r = tid & 63, grp = tid >> 6;
        int row = b * T_ + i0 + r;
        float4 ai[16];
        {
            const float4* rp = (const float4*)(xT + (size_t)row * 64);
            #pragma unroll
            for (int c4 = 0; c4 < 16; ++c4) ai[c4] = rp[c4];
        }
        int4 cA = *(const int4*)(cand + (size_t)row * 32 + grp * 8);
        int4 cB = *(const int4*)(cand + (size_t)row * 32 + grp * 8 + 4);
        int cl[8] = {cA.x, cA.y, cA.z, cA.w, cB.x, cB.y, cB.z, cB.w};
        const float INF = __builtin_inff();
        float D0 = INF, D1 = INF, D2 = INF;
        int   I0 = 0x7FFFFFFF, I1 = 0x7FFFFFFF, I2 = 0x7FFFFFFF;
        #pragma unroll
        for (int t = 0; t < 8; ++t) {
            int j = cl[t];
            const float4* bj = (const float4*)(xT + ((size_t)b * T_ + j) * 64);
            float px = 0.f, py = 0.f, pz = 0.f, pw = 0.f;
            #pragma unroll
            for (int c4 = 0; c4 < 16; ++c4) {
                float4 w = bj[c4];
                px = fmaf(w.x, ai[c4].x, px); py = fmaf(w.y, ai[c4].y, py);
                pz = fmaf(w.z, ai[c4].z, pz); pw = fmaf(w.w, ai[c4].w, pw);
            }
            float s = nsq[b * T_ + j] - 2.f * ((px + py) + (pz + pw));
            // (s, j) lexicographic insert (strict) == np stable top_k
            bool lt2 = (s < D2) || (s == D2 && j < I2);
            if (lt2) {
                bool lt1 = (s < D1) || (s == D1 && j < I1);
                if (lt1) {
                    D2 = D1; I2 = I1;
                    bool lt0 = (s < D0) || (s == D0 && j < I0);
                    if (lt0) { D1 = D0; I1 = I0; D0 = s; I0 = j; }
                    else     { D1 = s; I1 = j; }
                } else { D2 = s; I2 = j; }
            }
        }
        cs[r * 12 + grp * 3 + 0] = D0; cj[r * 12 + grp * 3 + 0] = I0;
        cs[r * 12 + grp * 3 + 1] = D1; cj[r * 12 + grp * 3 + 1] = I1;
        cs[r * 12 + grp * 3 + 2] = D2; cj[r * 12 + grp * 3 + 2] = I2;
    }
    __syncthreads();
    if (tid < 64) {     // merge 4 groups' top-3 -> global top-3
        const float INF = __builtin_inff();
        float D0 = INF, D1 = INF, D2 = INF;
        int   I0 = 0x7FFFFFFF, I1 = 0x7FFFFFFF, I2 = 0x7FFFFFFF;
        #pragma unroll
        for (int q = 0; q < 12; ++q) {
            float s = cs[tid * 12 + q]; int j = cj[tid * 12 + q];
            bool lt2 = (s < D2) || (s == D2 && j < I2);
            if (lt2) {
                bool lt1 = (s < D1) || (s == D1 && j < I1);
                if (lt1) {
                    D2 = D1; I2 = I1;
                    bool lt0 = (s < D0) || (s == D0 && j < I0);
                    if (lt0) { D1 = D0; I1 = I0; D0 = s; I0 = j; }
                    else     { D1 = s; I1 = j; }
                } else { D2 = s; I2 = j; }
            }
        }
        jsel[tid * 3 + 0] = I0; jsel[tid * 3 + 1] = I1; jsel[tid * 3 + 2] = I2;
    }
    __syncthreads();

    // --- Phase 2: gather 3 neighbor rows per i' into g_s[m][i']
    if (tid < 192) {
        int k  = tid >> 6;
        int ip = tid & 63;
        int j  = jsel[ip * 3 + k];
        const float4* src = (const float4*)(xT + ((size_t)b * T_ + j) * 64);
        #pragma unroll
        for (int c4 = 0; c4 < 16; ++c4) {
            float4 v = src[c4];
            int mm = k * 64 + c4 * 4;
            g_s[(mm + 0) * 64 + ip] = v.x;
            g_s[(mm + 1) * 64 + ip] = v.y;
            g_s[(mm + 2) * 64 + ip] = v.z;
            g_s[(mm + 3) * 64 + ip] = v.w;
        }
    }
    __syncthreads();

    // --- Phase 3: conv, 4o x 4i register tiles (identical math to R2)
    int oq = tid >> 4;
    int iq = tid & 15;
    float acc[4][4] = {{0.f}};
    #pragma unroll 4
    for (int mIt = 0; mIt < 192; ++mIt) {
        float4 wv = *(const float4*)(Wt_s + mIt * 64 + oq * 4);
        float4 gv = *(const float4*)(g_s  + mIt * 64 + iq * 4);
        acc[0][0] = fmaf(wv.x, gv.x, acc[0][0]); acc[0][1] = fmaf(wv.x, gv.y, acc[0][1]);
        acc[0][2] = fmaf(wv.x, gv.z, acc[0][2]); acc[0][3] = fmaf(wv.x, gv.w, acc[0][3]);
        acc[1][0] = fmaf(wv.y, gv.x, acc[1][0]); acc[1][1] = fmaf(wv.y, gv.y, acc[1][1]);
        acc[1][2] = fmaf(wv.y, gv.z, acc[1][2]); acc[1][3] = fmaf(wv.y, gv.w, acc[1][3]);
        acc[2][0] = fmaf(wv.z, gv.x, acc[2][0]); acc[2][1] = fmaf(wv.z, gv.y, acc[2][1]);
        acc[2][2] = fmaf(wv.z, gv.z, acc[2][2]); acc[2][3] = fmaf(wv.z, gv.w, acc[2][3]);
        acc[3][0] = fmaf(wv.w, gv.x, acc[3][0]); acc[3][1] = fmaf(wv.w, gv.y, acc[3][1]);
        acc[3][2] = fmaf(wv.w, gv.z, acc[3][2]); acc[3][3] = fmaf(wv.w, gv.w, acc[3][3]);
    }
    #pragma unroll
    for (int po = 0; po < 4; ++po) {
        int o = oq * 4 + po;
        float bv = bias[o];
        float4 r;
        r.x = acc[po][0] + bv; r.y = acc[po][1] + bv;
        r.z = acc[po][2] + bv; r.w = acc[po][3] + bv;
        *(float4*)(out + (b * O_ + o) * T_ + i0 + iq * 4) = r;
    }
}

// ---------------------------------------------------------------------------
extern "C" void kernel_launch(void* const* d_in, const int* in_sizes, int n_in,
                              void* d_out, int out_size, void* d_ws, size_t ws_size,
                              hipStream_t stream) {
    const float* x    = (const float*)d_in[0];
    const float* W    = (const float*)d_in[1];
    const float* bias = (const float*)d_in[2];
    float* out = (float*)d_out;
    float* ws  = (float*)d_ws;
    // requires ~21.2 MB workspace

    prep_kernel<<<B_ * (T_ / 64) + 48, 256, 0, stream>>>(x, W, ws);
    knn_mfma_kernel<<<1024, 256, 0, stream>>>(
        (const ushort*)(ws + XS_OFF), ws + NSQ_OFF, (int*)(ws + CAND_OFF));
    convref_kernel<<<B_ * 32, 256, 0, stream>>>(ws, bias, out);
}